// Round 4
// baseline (136.388 us; speedup 1.0000x reference)
//
#include <hip/hip_runtime.h>

static constexpr int IMG   = 512;
static constexpr int TX    = 64;    // output tile width
static constexpr int TY    = 32;    // output tile height
static constexpr int NTHR  = 256;   // 4 waves/block
static constexpr int LSTA  = 72;    // A row stride (floats), 16B aligned
static constexpr int LSTB  = 68;    // B row stride (floats), 16B aligned
static constexpr int AROWS = 36;    // A holds orig stage rows 1..36 (rows 0/37 read from global)
static constexpr int NSTAGE = AROWS * (LSTA / 4);   // 648 float4 items
// LDS: A 36*72*4 = 10368 B, B (36*68+2)*4 = 9800 B -> 20480 B alloc
// -> 8 blocks/CU * 4 waves = 32 waves/CU, grid 2048 fully co-resident.

// Edge-stopping accumulate, TRANS-FREE:
//   g(d)*d + acc  with  g = exp(-|d|/(1+d^2)).
// v = |d|/(1+d^2) is ALWAYS in [0, 0.5] (max at |d|=1), so e^{-v} is a
// degree-5 Taylor (max err 2.2e-5 on [0,0.5]). 1/(1+d^2) via bit-trick seed
// + 2 Newton steps (rel err ~6e-6). 13 VALU ops, zero rcp/exp2 -> frees the
// quarter-rate transcendental pipe that round-3 counters say we saturate.
__device__ __forceinline__ float gd_acc(float d, float acc) {
    const float t = fmaf(d, d, 1.0f);                       // t >= 1
    float r = __uint_as_float(0x7EF311C3u - __float_as_uint(t));
    r = r * fmaf(-t, r, 2.0f);                              // Newton 1
    r = r * fmaf(-t, r, 2.0f);                              // Newton 2
    const float v = __builtin_fabsf(d) * r;                 // in [0, 0.5]
    float e = fmaf(v, -1.0f/120.0f, 1.0f/24.0f);            // e^{-v}, deg-5
    e = fmaf(e, v, -1.0f/6.0f);
    e = fmaf(e, v,  0.5f);
    e = fmaf(e, v, -1.0f);
    e = fmaf(e, v,  1.0f);
    return fmaf(e, d, acc);
}

// 8 floats from global with per-float4 OOB predication (zeros = SAME padding).
__device__ __forceinline__ void ldg8(float* L, const float* __restrict__ img,
                                     int gy, int gx0) {
    float4 a = {0.f,0.f,0.f,0.f}, b = {0.f,0.f,0.f,0.f};
    if ((unsigned)gy < (unsigned)IMG) {
        const float* p = img + gy * IMG;
        if ((unsigned)gx0       < (unsigned)IMG) a = *(const float4*)(p + gx0);
        if ((unsigned)(gx0 + 4) < (unsigned)IMG) b = *(const float4*)(p + gx0 + 4);
    }
    *(float4*)&L[0] = a; *(float4*)&L[4] = b;
}

// Coordinate system (per block): stage col c <-> gx = tx0-4+c, stage row r
// (orig) <-> gy = ty0-3+r. A[j] = orig row j+1. B col c <-> gx = tx0-2+c,
// B[j] = step1-out row j+1. Step2 out col c <-> gx = tx0-1+c, stored A[r-1].
template<int WOFF, int NR, int RLO, int NG, int ILST, int OLST,
         bool HALOG, bool TO_GLOBAL>
__device__ __forceinline__ void diffuse_step(
    const float* __restrict__ prev, float* __restrict__ cur,
    const float* __restrict__ Wt, const float* __restrict__ bt,
    const float* __restrict__ xin, int xoff, int ty0, int tx0, int tid,
    float* __restrict__ gout)
{
    constexpr int NITEMS = NR * NG;
    for (int idx = tid; idx < NITEMS; idx += NTHR) {
        const int rr = idx / NG, j = idx - rr * NG;
        const int r  = RLO + rr, c0 = 4 * j;

        float L0[8], L1[8], L2[8];
        if (HALOG) {
            // step1: A holds orig rows 1..36; rows 0/37 come from global.
            const float* bc = prev + (r - 1) * ILST + c0;   // orig row r
            *(float4*)&L1[0] = *(const float4*)(bc);
            *(float4*)&L1[4] = *(const float4*)(bc + 4);
            if (r >= 2) {
                *(float4*)&L0[0] = *(const float4*)(bc - ILST);
                *(float4*)&L0[4] = *(const float4*)(bc - ILST + 4);
            } else {
                ldg8(L0, xin, ty0 - 3, tx0 - 4 + c0);
            }
            if (r <= AROWS - 1) {
                *(float4*)&L2[0] = *(const float4*)(bc + ILST);
                *(float4*)&L2[4] = *(const float4*)(bc + ILST + 4);
            } else {
                ldg8(L2, xin, ty0 + 34, tx0 - 4 + c0);
            }
        } else {
            const float* b0 = prev + (r - 2) * ILST + c0;
            *(float4*)&L0[0] = *(const float4*)(b0);
            *(float4*)&L1[0] = *(const float4*)(b0 + ILST);
            *(float4*)&L2[0] = *(const float4*)(b0 + 2 * ILST);
            *(float2*)&L0[4] = *(const float2*)(b0 + 4);
            *(float2*)&L1[4] = *(const float2*)(b0 + ILST + 4);
            *(float2*)&L2[4] = *(const float2*)(b0 + 2 * ILST + 4);
        }

        float acc[4] = {0.f, 0.f, 0.f, 0.f};
#pragma unroll
        for (int k = 0; k < 8; ++k) {
            const float w0 = Wt[9*k+0], w1 = Wt[9*k+1], w2 = Wt[9*k+2];
            const float w3 = Wt[9*k+3], w4 = Wt[9*k+4], w5 = Wt[9*k+5];
            const float w6 = Wt[9*k+6], w7 = Wt[9*k+7], w8 = Wt[9*k+8];
            const float bk = bt[k];
#pragma unroll
            for (int i = 0; i < 4; ++i) {
                float d = bk;
                d = fmaf(w0, L0[WOFF+i],   d);
                d = fmaf(w1, L0[WOFF+i+1], d);
                d = fmaf(w2, L0[WOFF+i+2], d);
                d = fmaf(w3, L1[WOFF+i],   d);
                d = fmaf(w4, L1[WOFF+i+1], d);
                d = fmaf(w5, L1[WOFF+i+2], d);
                d = fmaf(w6, L2[WOFF+i],   d);
                d = fmaf(w7, L2[WOFF+i+1], d);
                d = fmaf(w8, L2[WOFF+i+2], d);
                acc[i] = gd_acc(d, acc[i]);
            }
        }

        float4 v;
        v.x = L1[WOFF+1] - acc[0] * 0.125f;
        v.y = L1[WOFF+2] - acc[1] * 0.125f;
        v.z = L1[WOFF+3] - acc[2] * 0.125f;
        v.w = L1[WOFF+4] - acc[3] * 0.125f;

        const int gy = ty0 - 3 + r;
        if (TO_GLOBAL) {
            // step3: always fully interior to the image
            *(float4*)&gout[gy * IMG + tx0 + c0] = v;
        } else {
            // zero out-of-image pixels so the next step sees SAME zero padding
            const bool ry  = (unsigned)gy < (unsigned)IMG;
            const int  gx0 = xoff + c0;
            v.x = (ry && (unsigned)(gx0 + 0) < (unsigned)IMG) ? v.x : 0.f;
            v.y = (ry && (unsigned)(gx0 + 1) < (unsigned)IMG) ? v.y : 0.f;
            v.z = (ry && (unsigned)(gx0 + 2) < (unsigned)IMG) ? v.z : 0.f;
            v.w = (ry && (unsigned)(gx0 + 3) < (unsigned)IMG) ? v.w : 0.f;
            *(float4*)&cur[(r - 1) * OLST + c0] = v;
        }
    }
}

__global__ __launch_bounds__(NTHR) void deep_ad_fused8(
    const float* __restrict__ x, const float* __restrict__ W,
    const float* __restrict__ b, float* __restrict__ out)
{
    __shared__ float A [AROWS * LSTA];       // 2592 floats
    __shared__ float Bs[AROWS * LSTB + 2];   // 2450 floats (pad: step2 tail float2)

    const int tid = threadIdx.x;
    const int tx0 = blockIdx.x * TX;
    const int ty0 = blockIdx.y * TY;
    const float* xin  = x   + (size_t)blockIdx.z * (IMG * IMG);
    float*       gout = out + (size_t)blockIdx.z * (IMG * IMG);

    // ---- stage orig rows 1..36 into A (zeros outside image) ----
    {
        float4 sv[3];
#pragma unroll
        for (int q = 0; q < 3; ++q) {
            const int item = tid + NTHR * q;
            float4 v = {0.f, 0.f, 0.f, 0.f};
            if (item < NSTAGE) {
                const int rr = item / 18, jj = item - rr * 18;
                const int gy = ty0 - 2 + rr;        // orig row rr+1
                const int gx = tx0 - 4 + 4 * jj;    // float4 fully in or out
                if ((unsigned)gy < (unsigned)IMG && (unsigned)gx < (unsigned)IMG)
                    v = *(const float4*)(xin + gy * IMG + gx);
            }
            sv[q] = v;
        }
#pragma unroll
        for (int q = 0; q < 3; ++q) {
            const int item = tid + NTHR * q;
            if (item < NSTAGE) *(float4*)&A[item * 4] = sv[q];
        }
    }
    __syncthreads();

    // step1: orig rows 1..36 -> B rows 0..35 (68 cols)
    diffuse_step<1, 36, 1, 17, LSTA, LSTB, true,  false>(
        A,  Bs, W,       b,      xin, tx0 - 2, ty0, tx0, tid, nullptr);
    __syncthreads();
    // step2: B -> A rows 1..34 (step2-out row r at A[r-1])
    diffuse_step<0, 34, 2, 17, LSTB, LSTA, false, false>(
        Bs, A,  W + 72,  b + 8,  xin, tx0 - 1, ty0, tx0, tid, nullptr);
    __syncthreads();
    // step3: A -> global 64x32 tile
    diffuse_step<0, 32, 3, 16, LSTA, 0,    false, true >(
        A, nullptr, W + 144, b + 16, xin, 0, ty0, tx0, tid, gout);
}

extern "C" void kernel_launch(void* const* d_in, const int* in_sizes, int n_in,
                              void* d_out, int out_size, void* d_ws, size_t ws_size,
                              hipStream_t stream)
{
    const float* x = (const float*)d_in[0];
    const float* W = (const float*)d_in[1];  // [3,8,1,3,3]
    const float* b = (const float*)d_in[2];  // [3,8]
    float* out = (float*)d_out;
    const int N = in_sizes[0] / (IMG * IMG); // 16

    dim3 grid(IMG / TX, IMG / TY, N);        // (8, 16, 16) = 2048 blocks
    deep_ad_fused8<<<grid, NTHR, 0, stream>>>(x, W, b, out);
}

// Round 5
// 131.251 us; speedup vs baseline: 1.0391x; 1.0391x over previous
//
#include <hip/hip_runtime.h>

static constexpr int IMG = 512;

__device__ __forceinline__ float gd_acc(float d, float acc) {
    const float t    = fmaf(d, d, 1.0f);
    const float rinv = __builtin_amdgcn_rcpf(t);
    const float e    = __builtin_amdgcn_exp2f(
                           -1.442695040888963f * __builtin_fabsf(d) * rinv);
    return fmaf(e, d, acc);
}

// Load 12 floats (cols x0-4 .. x0+7) of row y; zeros outside the image.
__device__ __forceinline__ void load_row12(float* R, const float* __restrict__ src,
                                           int y, int x0, bool xfast) {
    const bool rowok = (unsigned)y < (unsigned)IMG;
    if (xfast && rowok) {
        const float* p = src + y * IMG + x0 - 4;   // 16B aligned
        *(float4*)&R[0] = *(const float4*)(p);
        *(float4*)&R[4] = *(const float4*)(p + 4);
        *(float4*)&R[8] = *(const float4*)(p + 8);
    } else {
#pragma unroll
        for (int j = 0; j < 12; ++j) {
            const int col = x0 - 4 + j;
            R[j] = (rowok && (unsigned)col < (unsigned)IMG)
                       ? src[y * IMG + col] : 0.f;
        }
    }
}

// One output row (4 px) from window rows RA(y-1), RB(y), RC(y+1).
// Pixel i center = array index i+4.
__device__ __forceinline__ float4 compute_row(
    const float* RA, const float* RB, const float* RC,
    const float* __restrict__ Wt, const float* __restrict__ bt)
{
    float acc[4] = {0.f, 0.f, 0.f, 0.f};
#pragma unroll
    for (int k = 0; k < 8; ++k) {
        const float w0 = Wt[9*k+0], w1 = Wt[9*k+1], w2 = Wt[9*k+2];
        const float w3 = Wt[9*k+3], w4 = Wt[9*k+4], w5 = Wt[9*k+5];
        const float w6 = Wt[9*k+6], w7 = Wt[9*k+7], w8 = Wt[9*k+8];
        const float bk = bt[k];
#pragma unroll
        for (int i = 0; i < 4; ++i) {
            float d = bk;
            d = fmaf(w0, RA[i+3], d);
            d = fmaf(w1, RA[i+4], d);
            d = fmaf(w2, RA[i+5], d);
            d = fmaf(w3, RB[i+3], d);
            d = fmaf(w4, RB[i+4], d);
            d = fmaf(w5, RB[i+5], d);
            d = fmaf(w6, RC[i+3], d);
            d = fmaf(w7, RC[i+4], d);
            d = fmaf(w8, RC[i+5], d);
            acc[i] = gd_acc(d, acc[i]);
        }
    }
    float4 v;
    v.x = RB[4] - acc[0] * 0.125f;
    v.y = RB[5] - acc[1] * 0.125f;
    v.z = RB[6] - acc[2] * 0.125f;
    v.w = RB[7] - acc[3] * 0.125f;
    return v;
}

// One diffusion step, global -> global, register row-blocked: each thread owns
// a 4-wide x 4-tall strip, sliding a 3-row register window down the column.
// Loads/px: 9 -> 4.5 floats vs the flat ad_step; prefetch of row y+r+2 is
// issued before computing row y+r so ~200cyc L2 latency hides under ~800cyc
// of conv math. No LDS, no barriers. Grid 1024 blocks = 4/CU, co-resident.
__global__ __launch_bounds__(256) void ad_step_rb(
    const float* __restrict__ in, float* __restrict__ outp,
    const float* __restrict__ Wt, const float* __restrict__ bt)
{
    const int tid = threadIdx.x;
    const int x0  = blockIdx.x * 64 + (tid & 15) * 4;   // 0,4,...,508
    const int y0  = blockIdx.y * 64 + (tid >> 4) * 4;   // 4-row strip base
    const float* __restrict__ src = in   + (size_t)blockIdx.z * (IMG * IMG);
    float*       __restrict__ dst = outp + (size_t)blockIdx.z * (IMG * IMG);
    const bool xfast = (x0 >= 4) && (x0 <= 504);

    float R0[12], R1[12], R2[12], R3[12];   // rotating window, all-static indices
    load_row12(R0, src, y0 - 1, x0, xfast);
    load_row12(R1, src, y0,     x0, xfast);
    load_row12(R2, src, y0 + 1, x0, xfast);

    // r=0: window R0,R1,R2 ; prefetch y0+2 into R3
    load_row12(R3, src, y0 + 2, x0, xfast);
    float4 v0 = compute_row(R0, R1, R2, Wt, bt);
    *(float4*)&dst[(y0 + 0) * IMG + x0] = v0;

    // r=1: window R1,R2,R3 ; prefetch y0+3 into R0
    load_row12(R0, src, y0 + 3, x0, xfast);
    float4 v1 = compute_row(R1, R2, R3, Wt, bt);
    *(float4*)&dst[(y0 + 1) * IMG + x0] = v1;

    // r=2: window R2,R3,R0 ; prefetch y0+4 into R1
    load_row12(R1, src, y0 + 4, x0, xfast);
    float4 v2 = compute_row(R2, R3, R0, Wt, bt);
    *(float4*)&dst[(y0 + 2) * IMG + x0] = v2;

    // r=3: window R3,R0,R1
    float4 v3 = compute_row(R3, R0, R1, Wt, bt);
    *(float4*)&dst[(y0 + 3) * IMG + x0] = v3;
}

// ---------------- fused fallback (round-3 kernel) if ws is too small ---------
static constexpr int TXF   = 64;
static constexpr int TYF   = 32;
static constexpr int NTHR  = 256;
static constexpr int LSTA  = 72;
static constexpr int LSTB  = 68;
static constexpr int AROWS = 36;
static constexpr int NSTAGE = AROWS * (LSTA / 4);

__device__ __forceinline__ void ldg8(float* L, const float* __restrict__ img,
                                     int gy, int gx0) {
    float4 a = {0.f,0.f,0.f,0.f}, b = {0.f,0.f,0.f,0.f};
    if ((unsigned)gy < (unsigned)IMG) {
        const float* p = img + gy * IMG;
        if ((unsigned)gx0       < (unsigned)IMG) a = *(const float4*)(p + gx0);
        if ((unsigned)(gx0 + 4) < (unsigned)IMG) b = *(const float4*)(p + gx0 + 4);
    }
    *(float4*)&L[0] = a; *(float4*)&L[4] = b;
}

template<int WOFF, int NR, int RLO, int NG, int ILST, int OLST,
         bool HALOG, bool TO_GLOBAL>
__device__ __forceinline__ void diffuse_step(
    const float* __restrict__ prev, float* __restrict__ cur,
    const float* __restrict__ Wt, const float* __restrict__ bt,
    const float* __restrict__ xin, int xoff, int ty0, int tx0, int tid,
    float* __restrict__ gout)
{
    constexpr int NITEMS = NR * NG;
    for (int idx = tid; idx < NITEMS; idx += NTHR) {
        const int rr = idx / NG, j = idx - rr * NG;
        const int r  = RLO + rr, c0 = 4 * j;

        float L0[8], L1[8], L2[8];
        if (HALOG) {
            const float* bc = prev + (r - 1) * ILST + c0;
            *(float4*)&L1[0] = *(const float4*)(bc);
            *(float4*)&L1[4] = *(const float4*)(bc + 4);
            if (r >= 2) {
                *(float4*)&L0[0] = *(const float4*)(bc - ILST);
                *(float4*)&L0[4] = *(const float4*)(bc - ILST + 4);
            } else {
                ldg8(L0, xin, ty0 - 3, tx0 - 4 + c0);
            }
            if (r <= AROWS - 1) {
                *(float4*)&L2[0] = *(const float4*)(bc + ILST);
                *(float4*)&L2[4] = *(const float4*)(bc + ILST + 4);
            } else {
                ldg8(L2, xin, ty0 + 34, tx0 - 4 + c0);
            }
        } else {
            const float* b0 = prev + (r - 2) * ILST + c0;
            *(float4*)&L0[0] = *(const float4*)(b0);
            *(float4*)&L1[0] = *(const float4*)(b0 + ILST);
            *(float4*)&L2[0] = *(const float4*)(b0 + 2 * ILST);
            *(float2*)&L0[4] = *(const float2*)(b0 + 4);
            *(float2*)&L1[4] = *(const float2*)(b0 + ILST + 4);
            *(float2*)&L2[4] = *(const float2*)(b0 + 2 * ILST + 4);
        }

        float acc[4] = {0.f, 0.f, 0.f, 0.f};
#pragma unroll
        for (int k = 0; k < 8; ++k) {
            const float w0 = Wt[9*k+0], w1 = Wt[9*k+1], w2 = Wt[9*k+2];
            const float w3 = Wt[9*k+3], w4 = Wt[9*k+4], w5 = Wt[9*k+5];
            const float w6 = Wt[9*k+6], w7 = Wt[9*k+7], w8 = Wt[9*k+8];
            const float bk = bt[k];
#pragma unroll
            for (int i = 0; i < 4; ++i) {
                float d = bk;
                d = fmaf(w0, L0[WOFF+i],   d);
                d = fmaf(w1, L0[WOFF+i+1], d);
                d = fmaf(w2, L0[WOFF+i+2], d);
                d = fmaf(w3, L1[WOFF+i],   d);
                d = fmaf(w4, L1[WOFF+i+1], d);
                d = fmaf(w5, L1[WOFF+i+2], d);
                d = fmaf(w6, L2[WOFF+i],   d);
                d = fmaf(w7, L2[WOFF+i+1], d);
                d = fmaf(w8, L2[WOFF+i+2], d);
                acc[i] = gd_acc(d, acc[i]);
            }
        }

        float4 v;
        v.x = L1[WOFF+1] - acc[0] * 0.125f;
        v.y = L1[WOFF+2] - acc[1] * 0.125f;
        v.z = L1[WOFF+3] - acc[2] * 0.125f;
        v.w = L1[WOFF+4] - acc[3] * 0.125f;

        const int gy = ty0 - 3 + r;
        if (TO_GLOBAL) {
            *(float4*)&gout[gy * IMG + tx0 + c0] = v;
        } else {
            const bool ry  = (unsigned)gy < (unsigned)IMG;
            const int  gx0 = xoff + c0;
            v.x = (ry && (unsigned)(gx0 + 0) < (unsigned)IMG) ? v.x : 0.f;
            v.y = (ry && (unsigned)(gx0 + 1) < (unsigned)IMG) ? v.y : 0.f;
            v.z = (ry && (unsigned)(gx0 + 2) < (unsigned)IMG) ? v.z : 0.f;
            v.w = (ry && (unsigned)(gx0 + 3) < (unsigned)IMG) ? v.w : 0.f;
            *(float4*)&cur[(r - 1) * OLST + c0] = v;
        }
    }
}

__global__ __launch_bounds__(NTHR) void deep_ad_fused8(
    const float* __restrict__ x, const float* __restrict__ W,
    const float* __restrict__ b, float* __restrict__ out)
{
    __shared__ float A [AROWS * LSTA];
    __shared__ float Bs[AROWS * LSTB + 2];

    const int tid = threadIdx.x;
    const int tx0 = blockIdx.x * TXF;
    const int ty0 = blockIdx.y * TYF;
    const float* xin  = x   + (size_t)blockIdx.z * (IMG * IMG);
    float*       gout = out + (size_t)blockIdx.z * (IMG * IMG);

    {
        float4 sv[3];
#pragma unroll
        for (int q = 0; q < 3; ++q) {
            const int item = tid + NTHR * q;
            float4 v = {0.f, 0.f, 0.f, 0.f};
            if (item < NSTAGE) {
                const int rr = item / 18, jj = item - rr * 18;
                const int gy = ty0 - 2 + rr;
                const int gx = tx0 - 4 + 4 * jj;
                if ((unsigned)gy < (unsigned)IMG && (unsigned)gx < (unsigned)IMG)
                    v = *(const float4*)(xin + gy * IMG + gx);
            }
            sv[q] = v;
        }
#pragma unroll
        for (int q = 0; q < 3; ++q) {
            const int item = tid + NTHR * q;
            if (item < NSTAGE) *(float4*)&A[item * 4] = sv[q];
        }
    }
    __syncthreads();

    diffuse_step<1, 36, 1, 17, LSTA, LSTB, true,  false>(
        A,  Bs, W,       b,      xin, tx0 - 2, ty0, tx0, tid, nullptr);
    __syncthreads();
    diffuse_step<0, 34, 2, 17, LSTB, LSTA, false, false>(
        Bs, A,  W + 72,  b + 8,  xin, tx0 - 1, ty0, tx0, tid, nullptr);
    __syncthreads();
    diffuse_step<0, 32, 3, 16, LSTA, 0,    false, true >(
        A, nullptr, W + 144, b + 16, xin, 0, ty0, tx0, tid, gout);
}

extern "C" void kernel_launch(void* const* d_in, const int* in_sizes, int n_in,
                              void* d_out, int out_size, void* d_ws, size_t ws_size,
                              hipStream_t stream)
{
    const float* x = (const float*)d_in[0];
    const float* W = (const float*)d_in[1];  // [3,8,1,3,3]
    const float* b = (const float*)d_in[2];  // [3,8]
    float* out = (float*)d_out;
    const int N = in_sizes[0] / (IMG * IMG); // 16

    const size_t imgBytes = (size_t)N * IMG * IMG * sizeof(float);
    if (ws_size >= imgBytes) {
        float* ws = (float*)d_ws;
        dim3 g(IMG / 64, IMG / 64, N);       // (8, 8, 16) = 1024 blocks
        // x -> out -> ws -> out (each pass fully writes dest before next reads)
        ad_step_rb<<<g, 256, 0, stream>>>(x,   out, W + 0,   b + 0);
        ad_step_rb<<<g, 256, 0, stream>>>(out, ws,  W + 72,  b + 8);
        ad_step_rb<<<g, 256, 0, stream>>>(ws,  out, W + 144, b + 16);
    } else {
        dim3 grid(IMG / TXF, IMG / TYF, N);
        deep_ad_fused8<<<grid, NTHR, 0, stream>>>(x, W, b, out);
    }
}

// Round 6
// 118.489 us; speedup vs baseline: 1.1511x; 1.1077x over previous
//
#include <hip/hip_runtime.h>

static constexpr int IMG = 512;

__device__ __forceinline__ float gd_acc(float d, float acc) {
    const float t    = fmaf(d, d, 1.0f);
    const float rinv = __builtin_amdgcn_rcpf(t);
    const float e    = __builtin_amdgcn_exp2f(
                           -1.442695040888963f * __builtin_fabsf(d) * rinv);
    return fmaf(e, d, acc);
}

// Load 12 floats (cols x0-4 .. x0+7) of row y; zeros outside the image.
__device__ __forceinline__ void load_row12(float* R, const float* __restrict__ src,
                                           int y, int x0, bool xfast) {
    const bool rowok = (unsigned)y < (unsigned)IMG;
    if (xfast && rowok) {
        const float* p = src + y * IMG + x0 - 4;   // 16B aligned
        *(float4*)&R[0] = *(const float4*)(p);
        *(float4*)&R[4] = *(const float4*)(p + 4);
        *(float4*)&R[8] = *(const float4*)(p + 8);
    } else {
#pragma unroll
        for (int j = 0; j < 12; ++j) {
            const int col = x0 - 4 + j;
            R[j] = (rowok && (unsigned)col < (unsigned)IMG)
                       ? src[y * IMG + col] : 0.f;
        }
    }
}

// One output row (4 px) from window rows RA(y-1), RB(y), RC(y+1).
// Pixel i center = array index i+4.
__device__ __forceinline__ float4 compute_row(
    const float* RA, const float* RB, const float* RC,
    const float* __restrict__ Wt, const float* __restrict__ bt)
{
    float acc[4] = {0.f, 0.f, 0.f, 0.f};
#pragma unroll
    for (int k = 0; k < 8; ++k) {
        const float w0 = Wt[9*k+0], w1 = Wt[9*k+1], w2 = Wt[9*k+2];
        const float w3 = Wt[9*k+3], w4 = Wt[9*k+4], w5 = Wt[9*k+5];
        const float w6 = Wt[9*k+6], w7 = Wt[9*k+7], w8 = Wt[9*k+8];
        const float bk = bt[k];
#pragma unroll
        for (int i = 0; i < 4; ++i) {
            float d = bk;
            d = fmaf(w0, RA[i+3], d);
            d = fmaf(w1, RA[i+4], d);
            d = fmaf(w2, RA[i+5], d);
            d = fmaf(w3, RB[i+3], d);
            d = fmaf(w4, RB[i+4], d);
            d = fmaf(w5, RB[i+5], d);
            d = fmaf(w6, RC[i+3], d);
            d = fmaf(w7, RC[i+4], d);
            d = fmaf(w8, RC[i+5], d);
            acc[i] = gd_acc(d, acc[i]);
        }
    }
    float4 v;
    v.x = RB[4] - acc[0] * 0.125f;
    v.y = RB[5] - acc[1] * 0.125f;
    v.z = RB[6] - acc[2] * 0.125f;
    v.w = RB[7] - acc[3] * 0.125f;
    return v;
}

// One diffusion step, global -> global. Each thread: 4 px wide x 2 rows.
// 12 independent float4 loads issued up-front (rows y-1..y+2), row-y math can
// start at vmcnt(3). Loads/px 1.5 insts (vs 2.25 flat), prologue amortized 2x.
// Grid 2048 blocks x 4 waves = 32 waves/CU supply; VGPR ~70-84 -> 6-7/SIMD.
// No LDS, no barriers.
__global__ __launch_bounds__(256) void ad_step2(
    const float* __restrict__ in, float* __restrict__ outp,
    const float* __restrict__ Wt, const float* __restrict__ bt)
{
    const int tid = threadIdx.x;
    const int x0  = blockIdx.x * 64 + (tid & 15) * 4;   // 0,4,...,508
    const int y0  = blockIdx.y * 32 + (tid >> 4) * 2;   // 2-row strip base
    const float* __restrict__ src = in   + (size_t)blockIdx.z * (IMG * IMG);
    float*       __restrict__ dst = outp + (size_t)blockIdx.z * (IMG * IMG);
    const bool xfast = (x0 >= 4) && (x0 <= 504);

    float R0[12], R1[12], R2[12], R3[12];
    load_row12(R0, src, y0 - 1, x0, xfast);
    load_row12(R1, src, y0,     x0, xfast);
    load_row12(R2, src, y0 + 1, x0, xfast);
    load_row12(R3, src, y0 + 2, x0, xfast);

    const float4 v0 = compute_row(R0, R1, R2, Wt, bt);
    *(float4*)&dst[(y0 + 0) * IMG + x0] = v0;
    const float4 v1 = compute_row(R1, R2, R3, Wt, bt);
    *(float4*)&dst[(y0 + 1) * IMG + x0] = v1;
}

// ---------------- fused fallback (round-3 kernel) if ws is too small ---------
static constexpr int TXF   = 64;
static constexpr int TYF   = 32;
static constexpr int NTHR  = 256;
static constexpr int LSTA  = 72;
static constexpr int LSTB  = 68;
static constexpr int AROWS = 36;
static constexpr int NSTAGE = AROWS * (LSTA / 4);

__device__ __forceinline__ void ldg8(float* L, const float* __restrict__ img,
                                     int gy, int gx0) {
    float4 a = {0.f,0.f,0.f,0.f}, b = {0.f,0.f,0.f,0.f};
    if ((unsigned)gy < (unsigned)IMG) {
        const float* p = img + gy * IMG;
        if ((unsigned)gx0       < (unsigned)IMG) a = *(const float4*)(p + gx0);
        if ((unsigned)(gx0 + 4) < (unsigned)IMG) b = *(const float4*)(p + gx0 + 4);
    }
    *(float4*)&L[0] = a; *(float4*)&L[4] = b;
}

template<int WOFF, int NR, int RLO, int NG, int ILST, int OLST,
         bool HALOG, bool TO_GLOBAL>
__device__ __forceinline__ void diffuse_step(
    const float* __restrict__ prev, float* __restrict__ cur,
    const float* __restrict__ Wt, const float* __restrict__ bt,
    const float* __restrict__ xin, int xoff, int ty0, int tx0, int tid,
    float* __restrict__ gout)
{
    constexpr int NITEMS = NR * NG;
    for (int idx = tid; idx < NITEMS; idx += NTHR) {
        const int rr = idx / NG, j = idx - rr * NG;
        const int r  = RLO + rr, c0 = 4 * j;

        float L0[8], L1[8], L2[8];
        if (HALOG) {
            const float* bc = prev + (r - 1) * ILST + c0;
            *(float4*)&L1[0] = *(const float4*)(bc);
            *(float4*)&L1[4] = *(const float4*)(bc + 4);
            if (r >= 2) {
                *(float4*)&L0[0] = *(const float4*)(bc - ILST);
                *(float4*)&L0[4] = *(const float4*)(bc - ILST + 4);
            } else {
                ldg8(L0, xin, ty0 - 3, tx0 - 4 + c0);
            }
            if (r <= AROWS - 1) {
                *(float4*)&L2[0] = *(const float4*)(bc + ILST);
                *(float4*)&L2[4] = *(const float4*)(bc + ILST + 4);
            } else {
                ldg8(L2, xin, ty0 + 34, tx0 - 4 + c0);
            }
        } else {
            const float* b0 = prev + (r - 2) * ILST + c0;
            *(float4*)&L0[0] = *(const float4*)(b0);
            *(float4*)&L1[0] = *(const float4*)(b0 + ILST);
            *(float4*)&L2[0] = *(const float4*)(b0 + 2 * ILST);
            *(float2*)&L0[4] = *(const float2*)(b0 + 4);
            *(float2*)&L1[4] = *(const float2*)(b0 + ILST + 4);
            *(float2*)&L2[4] = *(const float2*)(b0 + 2 * ILST + 4);
        }

        float acc[4] = {0.f, 0.f, 0.f, 0.f};
#pragma unroll
        for (int k = 0; k < 8; ++k) {
            const float w0 = Wt[9*k+0], w1 = Wt[9*k+1], w2 = Wt[9*k+2];
            const float w3 = Wt[9*k+3], w4 = Wt[9*k+4], w5 = Wt[9*k+5];
            const float w6 = Wt[9*k+6], w7 = Wt[9*k+7], w8 = Wt[9*k+8];
            const float bk = bt[k];
#pragma unroll
            for (int i = 0; i < 4; ++i) {
                float d = bk;
                d = fmaf(w0, L0[WOFF+i],   d);
                d = fmaf(w1, L0[WOFF+i+1], d);
                d = fmaf(w2, L0[WOFF+i+2], d);
                d = fmaf(w3, L1[WOFF+i],   d);
                d = fmaf(w4, L1[WOFF+i+1], d);
                d = fmaf(w5, L1[WOFF+i+2], d);
                d = fmaf(w6, L2[WOFF+i],   d);
                d = fmaf(w7, L2[WOFF+i+1], d);
                d = fmaf(w8, L2[WOFF+i+2], d);
                acc[i] = gd_acc(d, acc[i]);
            }
        }

        float4 v;
        v.x = L1[WOFF+1] - acc[0] * 0.125f;
        v.y = L1[WOFF+2] - acc[1] * 0.125f;
        v.z = L1[WOFF+3] - acc[2] * 0.125f;
        v.w = L1[WOFF+4] - acc[3] * 0.125f;

        const int gy = ty0 - 3 + r;
        if (TO_GLOBAL) {
            *(float4*)&gout[gy * IMG + tx0 + c0] = v;
        } else {
            const bool ry  = (unsigned)gy < (unsigned)IMG;
            const int  gx0 = xoff + c0;
            v.x = (ry && (unsigned)(gx0 + 0) < (unsigned)IMG) ? v.x : 0.f;
            v.y = (ry && (unsigned)(gx0 + 1) < (unsigned)IMG) ? v.y : 0.f;
            v.z = (ry && (unsigned)(gx0 + 2) < (unsigned)IMG) ? v.z : 0.f;
            v.w = (ry && (unsigned)(gx0 + 3) < (unsigned)IMG) ? v.w : 0.f;
            *(float4*)&cur[(r - 1) * OLST + c0] = v;
        }
    }
}

__global__ __launch_bounds__(NTHR) void deep_ad_fused8(
    const float* __restrict__ x, const float* __restrict__ W,
    const float* __restrict__ b, float* __restrict__ out)
{
    __shared__ float A [AROWS * LSTA];
    __shared__ float Bs[AROWS * LSTB + 2];

    const int tid = threadIdx.x;
    const int tx0 = blockIdx.x * TXF;
    const int ty0 = blockIdx.y * TYF;
    const float* xin  = x   + (size_t)blockIdx.z * (IMG * IMG);
    float*       gout = out + (size_t)blockIdx.z * (IMG * IMG);

    {
        float4 sv[3];
#pragma unroll
        for (int q = 0; q < 3; ++q) {
            const int item = tid + NTHR * q;
            float4 v = {0.f, 0.f, 0.f, 0.f};
            if (item < NSTAGE) {
                const int rr = item / 18, jj = item - rr * 18;
                const int gy = ty0 - 2 + rr;
                const int gx = tx0 - 4 + 4 * jj;
                if ((unsigned)gy < (unsigned)IMG && (unsigned)gx < (unsigned)IMG)
                    v = *(const float4*)(xin + gy * IMG + gx);
            }
            sv[q] = v;
        }
#pragma unroll
        for (int q = 0; q < 3; ++q) {
            const int item = tid + NTHR * q;
            if (item < NSTAGE) *(float4*)&A[item * 4] = sv[q];
        }
    }
    __syncthreads();

    diffuse_step<1, 36, 1, 17, LSTA, LSTB, true,  false>(
        A,  Bs, W,       b,      xin, tx0 - 2, ty0, tx0, tid, nullptr);
    __syncthreads();
    diffuse_step<0, 34, 2, 17, LSTB, LSTA, false, false>(
        Bs, A,  W + 72,  b + 8,  xin, tx0 - 1, ty0, tx0, tid, nullptr);
    __syncthreads();
    diffuse_step<0, 32, 3, 16, LSTA, 0,    false, true >(
        A, nullptr, W + 144, b + 16, xin, 0, ty0, tx0, tid, gout);
}

extern "C" void kernel_launch(void* const* d_in, const int* in_sizes, int n_in,
                              void* d_out, int out_size, void* d_ws, size_t ws_size,
                              hipStream_t stream)
{
    const float* x = (const float*)d_in[0];
    const float* W = (const float*)d_in[1];  // [3,8,1,3,3]
    const float* b = (const float*)d_in[2];  // [3,8]
    float* out = (float*)d_out;
    const int N = in_sizes[0] / (IMG * IMG); // 16

    const size_t imgBytes = (size_t)N * IMG * IMG * sizeof(float);
    if (ws_size >= imgBytes) {
        float* ws = (float*)d_ws;
        dim3 g(IMG / 64, IMG / 32, N);       // (8, 16, 16) = 2048 blocks
        // x -> out -> ws -> out (each pass fully writes dest before next reads)
        ad_step2<<<g, 256, 0, stream>>>(x,   out, W + 0,   b + 0);
        ad_step2<<<g, 256, 0, stream>>>(out, ws,  W + 72,  b + 8);
        ad_step2<<<g, 256, 0, stream>>>(ws,  out, W + 144, b + 16);
    } else {
        dim3 grid(IMG / TXF, IMG / TYF, N);
        deep_ad_fused8<<<grid, NTHR, 0, stream>>>(x, W, b, out);
    }
}

// Round 7
// 116.000 us; speedup vs baseline: 1.1758x; 1.0215x over previous
//
#include <hip/hip_runtime.h>

static constexpr int IMG = 512;

typedef float v2f __attribute__((ext_vector_type(2)));

__device__ __forceinline__ v2f pkfma(v2f a, v2f b, v2f c) {
    return __builtin_elementwise_fma(a, b, c);   // -> v_pk_fma_f32 on gfx950
}

// Packed edge-stopping accumulate for a pixel pair:
// acc += exp(-|d|/(1+d^2)) * d. t and the final accumulate are packed
// (v_pk_fma_f32); rcp/exp2 and the |d|*c*rinv muls stay scalar (trans has no
// packed form; abs is a free VOP3 modifier on the scalar mul).
__device__ __forceinline__ v2f gd_acc2(v2f d, v2f acc) {
    const v2f t = pkfma(d, d, (v2f){1.0f, 1.0f});
    v2f e;
    e.x = __builtin_amdgcn_exp2f(-1.442695040888963f * __builtin_fabsf(d.x)
                                 * __builtin_amdgcn_rcpf(t.x));
    e.y = __builtin_amdgcn_exp2f(-1.442695040888963f * __builtin_fabsf(d.y)
                                 * __builtin_amdgcn_rcpf(t.y));
    return pkfma(e, d, acc);
}

// -------- One diffusion step, global -> global. Round-0 geometry EXACTLY
// (4096 blocks, 256 thr, 1 item = 4 px/thread, no LDS, no barriers) — the
// measured-best shape. Only change: conv + g computed as packed f32 pairs,
// cutting ~550 -> ~390 issue slots per item (v_pk_fma_f32 = 2 FMA/inst).
__global__ __launch_bounds__(256) void ad_step_pk(
    const float* __restrict__ in, float* __restrict__ outp,
    const float* __restrict__ Wt, const float* __restrict__ bt)
{
    const int tid = threadIdx.x;
    const int x0  = blockIdx.x * 64 + (tid & 15) * 4;   // 0,4,...,508
    const int y   = blockIdx.y * 16 + (tid >> 4);       // 0..511
    const float* __restrict__ src = in + (size_t)blockIdx.z * (IMG * IMG);

    float L[3][12];
    const bool xfast = (x0 >= 4) && (x0 <= 504);        // cols x0-4..x0+7 in-image
#pragma unroll
    for (int dy = 0; dy < 3; ++dy) {
        const int yy = y + dy - 1;
        const bool rowok = (unsigned)yy < (unsigned)IMG;
        if (xfast && rowok) {
            const float* p = src + yy * IMG + x0 - 4;   // 16B-aligned
            *(float4*)&L[dy][0] = *(const float4*)(p);
            *(float4*)&L[dy][4] = *(const float4*)(p + 4);
            *(float4*)&L[dy][8] = *(const float4*)(p + 8);
        } else {
#pragma unroll
            for (int j = 0; j < 12; ++j) {
                const int col = x0 - 4 + j;
                L[dy][j] = (rowok && (unsigned)col < (unsigned)IMG)
                               ? src[yy * IMG + col] : 0.f;
            }
        }
    }

    // Overlapping tap pairs, built once (k-invariant): P[r][j] = {L[r][3+j], L[r][4+j]}.
    // Pixel pair (0,1) uses P[r][0..2]; pair (2,3) uses P[r][2..4] (P[r][2] shared).
    v2f P[3][5];
#pragma unroll
    for (int r = 0; r < 3; ++r)
#pragma unroll
        for (int j = 0; j < 5; ++j)
            P[r][j] = (v2f){L[r][3 + j], L[r][4 + j]};

    v2f acc0 = {0.f, 0.f}, acc1 = {0.f, 0.f};
#pragma unroll
    for (int k = 0; k < 8; ++k) {
        const float w0 = Wt[9*k+0], w1 = Wt[9*k+1], w2 = Wt[9*k+2];
        const float w3 = Wt[9*k+3], w4 = Wt[9*k+4], w5 = Wt[9*k+5];
        const float w6 = Wt[9*k+6], w7 = Wt[9*k+7], w8 = Wt[9*k+8];
        const float bk = bt[k];

        v2f d0 = {bk, bk}, d1 = {bk, bk};
        d0 = pkfma((v2f){w0, w0}, P[0][0], d0);  d1 = pkfma((v2f){w0, w0}, P[0][2], d1);
        d0 = pkfma((v2f){w1, w1}, P[0][1], d0);  d1 = pkfma((v2f){w1, w1}, P[0][3], d1);
        d0 = pkfma((v2f){w2, w2}, P[0][2], d0);  d1 = pkfma((v2f){w2, w2}, P[0][4], d1);
        d0 = pkfma((v2f){w3, w3}, P[1][0], d0);  d1 = pkfma((v2f){w3, w3}, P[1][2], d1);
        d0 = pkfma((v2f){w4, w4}, P[1][1], d0);  d1 = pkfma((v2f){w4, w4}, P[1][3], d1);
        d0 = pkfma((v2f){w5, w5}, P[1][2], d0);  d1 = pkfma((v2f){w5, w5}, P[1][4], d1);
        d0 = pkfma((v2f){w6, w6}, P[2][0], d0);  d1 = pkfma((v2f){w6, w6}, P[2][2], d1);
        d0 = pkfma((v2f){w7, w7}, P[2][1], d0);  d1 = pkfma((v2f){w7, w7}, P[2][3], d1);
        d0 = pkfma((v2f){w8, w8}, P[2][2], d0);  d1 = pkfma((v2f){w8, w8}, P[2][4], d1);

        acc0 = gd_acc2(d0, acc0);
        acc1 = gd_acc2(d1, acc1);
    }

    float4 v;
    v.x = L[1][4] - acc0.x * 0.125f;
    v.y = L[1][5] - acc0.y * 0.125f;
    v.z = L[1][6] - acc1.x * 0.125f;
    v.w = L[1][7] - acc1.y * 0.125f;
    *(float4*)&outp[(size_t)blockIdx.z * (IMG * IMG) + y * IMG + x0] = v;
}

// ---------------- fused fallback (round-3 kernel) if ws is too small ---------
static constexpr int TXF   = 64;
static constexpr int TYF   = 32;
static constexpr int NTHR  = 256;
static constexpr int LSTA  = 72;
static constexpr int LSTB  = 68;
static constexpr int AROWS = 36;
static constexpr int NSTAGE = AROWS * (LSTA / 4);

__device__ __forceinline__ float gd_acc(float d, float acc) {
    const float t    = fmaf(d, d, 1.0f);
    const float rinv = __builtin_amdgcn_rcpf(t);
    const float e    = __builtin_amdgcn_exp2f(
                           -1.442695040888963f * __builtin_fabsf(d) * rinv);
    return fmaf(e, d, acc);
}

__device__ __forceinline__ void ldg8(float* L, const float* __restrict__ img,
                                     int gy, int gx0) {
    float4 a = {0.f,0.f,0.f,0.f}, b = {0.f,0.f,0.f,0.f};
    if ((unsigned)gy < (unsigned)IMG) {
        const float* p = img + gy * IMG;
        if ((unsigned)gx0       < (unsigned)IMG) a = *(const float4*)(p + gx0);
        if ((unsigned)(gx0 + 4) < (unsigned)IMG) b = *(const float4*)(p + gx0 + 4);
    }
    *(float4*)&L[0] = a; *(float4*)&L[4] = b;
}

template<int WOFF, int NR, int RLO, int NG, int ILST, int OLST,
         bool HALOG, bool TO_GLOBAL>
__device__ __forceinline__ void diffuse_step(
    const float* __restrict__ prev, float* __restrict__ cur,
    const float* __restrict__ Wt, const float* __restrict__ bt,
    const float* __restrict__ xin, int xoff, int ty0, int tx0, int tid,
    float* __restrict__ gout)
{
    constexpr int NITEMS = NR * NG;
    for (int idx = tid; idx < NITEMS; idx += NTHR) {
        const int rr = idx / NG, j = idx - rr * NG;
        const int r  = RLO + rr, c0 = 4 * j;

        float L0[8], L1[8], L2[8];
        if (HALOG) {
            const float* bc = prev + (r - 1) * ILST + c0;
            *(float4*)&L1[0] = *(const float4*)(bc);
            *(float4*)&L1[4] = *(const float4*)(bc + 4);
            if (r >= 2) {
                *(float4*)&L0[0] = *(const float4*)(bc - ILST);
                *(float4*)&L0[4] = *(const float4*)(bc - ILST + 4);
            } else {
                ldg8(L0, xin, ty0 - 3, tx0 - 4 + c0);
            }
            if (r <= AROWS - 1) {
                *(float4*)&L2[0] = *(const float4*)(bc + ILST);
                *(float4*)&L2[4] = *(const float4*)(bc + ILST + 4);
            } else {
                ldg8(L2, xin, ty0 + 34, tx0 - 4 + c0);
            }
        } else {
            const float* b0 = prev + (r - 2) * ILST + c0;
            *(float4*)&L0[0] = *(const float4*)(b0);
            *(float4*)&L1[0] = *(const float4*)(b0 + ILST);
            *(float4*)&L2[0] = *(const float4*)(b0 + 2 * ILST);
            *(float2*)&L0[4] = *(const float2*)(b0 + 4);
            *(float2*)&L1[4] = *(const float2*)(b0 + ILST + 4);
            *(float2*)&L2[4] = *(const float2*)(b0 + 2 * ILST + 4);
        }

        float acc[4] = {0.f, 0.f, 0.f, 0.f};
#pragma unroll
        for (int k = 0; k < 8; ++k) {
            const float w0 = Wt[9*k+0], w1 = Wt[9*k+1], w2 = Wt[9*k+2];
            const float w3 = Wt[9*k+3], w4 = Wt[9*k+4], w5 = Wt[9*k+5];
            const float w6 = Wt[9*k+6], w7 = Wt[9*k+7], w8 = Wt[9*k+8];
            const float bk = bt[k];
#pragma unroll
            for (int i = 0; i < 4; ++i) {
                float d = bk;
                d = fmaf(w0, L0[WOFF+i],   d);
                d = fmaf(w1, L0[WOFF+i+1], d);
                d = fmaf(w2, L0[WOFF+i+2], d);
                d = fmaf(w3, L1[WOFF+i],   d);
                d = fmaf(w4, L1[WOFF+i+1], d);
                d = fmaf(w5, L1[WOFF+i+2], d);
                d = fmaf(w6, L2[WOFF+i],   d);
                d = fmaf(w7, L2[WOFF+i+1], d);
                d = fmaf(w8, L2[WOFF+i+2], d);
                acc[i] = gd_acc(d, acc[i]);
            }
        }

        float4 v;
        v.x = L1[WOFF+1] - acc[0] * 0.125f;
        v.y = L1[WOFF+2] - acc[1] * 0.125f;
        v.z = L1[WOFF+3] - acc[2] * 0.125f;
        v.w = L1[WOFF+4] - acc[3] * 0.125f;

        const int gy = ty0 - 3 + r;
        if (TO_GLOBAL) {
            *(float4*)&gout[gy * IMG + tx0 + c0] = v;
        } else {
            const bool ry  = (unsigned)gy < (unsigned)IMG;
            const int  gx0 = xoff + c0;
            v.x = (ry && (unsigned)(gx0 + 0) < (unsigned)IMG) ? v.x : 0.f;
            v.y = (ry && (unsigned)(gx0 + 1) < (unsigned)IMG) ? v.y : 0.f;
            v.z = (ry && (unsigned)(gx0 + 2) < (unsigned)IMG) ? v.z : 0.f;
            v.w = (ry && (unsigned)(gx0 + 3) < (unsigned)IMG) ? v.w : 0.f;
            *(float4*)&cur[(r - 1) * OLST + c0] = v;
        }
    }
}

__global__ __launch_bounds__(NTHR) void deep_ad_fused8(
    const float* __restrict__ x, const float* __restrict__ W,
    const float* __restrict__ b, float* __restrict__ out)
{
    __shared__ float A [AROWS * LSTA];
    __shared__ float Bs[AROWS * LSTB + 2];

    const int tid = threadIdx.x;
    const int tx0 = blockIdx.x * TXF;
    const int ty0 = blockIdx.y * TYF;
    const float* xin  = x   + (size_t)blockIdx.z * (IMG * IMG);
    float*       gout = out + (size_t)blockIdx.z * (IMG * IMG);

    {
        float4 sv[3];
#pragma unroll
        for (int q = 0; q < 3; ++q) {
            const int item = tid + NTHR * q;
            float4 v = {0.f, 0.f, 0.f, 0.f};
            if (item < NSTAGE) {
                const int rr = item / 18, jj = item - rr * 18;
                const int gy = ty0 - 2 + rr;
                const int gx = tx0 - 4 + 4 * jj;
                if ((unsigned)gy < (unsigned)IMG && (unsigned)gx < (unsigned)IMG)
                    v = *(const float4*)(xin + gy * IMG + gx);
            }
            sv[q] = v;
        }
#pragma unroll
        for (int q = 0; q < 3; ++q) {
            const int item = tid + NTHR * q;
            if (item < NSTAGE) *(float4*)&A[item * 4] = sv[q];
        }
    }
    __syncthreads();

    diffuse_step<1, 36, 1, 17, LSTA, LSTB, true,  false>(
        A,  Bs, W,       b,      xin, tx0 - 2, ty0, tx0, tid, nullptr);
    __syncthreads();
    diffuse_step<0, 34, 2, 17, LSTB, LSTA, false, false>(
        Bs, A,  W + 72,  b + 8,  xin, tx0 - 1, ty0, tx0, tid, nullptr);
    __syncthreads();
    diffuse_step<0, 32, 3, 16, LSTA, 0,    false, true >(
        A, nullptr, W + 144, b + 16, xin, 0, ty0, tx0, tid, gout);
}

extern "C" void kernel_launch(void* const* d_in, const int* in_sizes, int n_in,
                              void* d_out, int out_size, void* d_ws, size_t ws_size,
                              hipStream_t stream)
{
    const float* x = (const float*)d_in[0];
    const float* W = (const float*)d_in[1];  // [3,8,1,3,3]
    const float* b = (const float*)d_in[2];  // [3,8]
    float* out = (float*)d_out;
    const int N = in_sizes[0] / (IMG * IMG); // 16

    const size_t imgBytes = (size_t)N * IMG * IMG * sizeof(float);
    if (ws_size >= imgBytes) {
        float* ws = (float*)d_ws;
        dim3 g(IMG / 64, IMG / 16, N);       // (8, 32, 16) = 4096 blocks
        // x -> out -> ws -> out (each pass fully writes dest before next reads)
        ad_step_pk<<<g, 256, 0, stream>>>(x,   out, W + 0,   b + 0);
        ad_step_pk<<<g, 256, 0, stream>>>(out, ws,  W + 72,  b + 8);
        ad_step_pk<<<g, 256, 0, stream>>>(ws,  out, W + 144, b + 16);
    } else {
        dim3 grid(IMG / TXF, IMG / TYF, N);
        deep_ad_fused8<<<grid, NTHR, 0, stream>>>(x, W, b, out);
    }
}